// Round 12
// baseline (94.895 us; speedup 1.0000x reference)
//
#include <hip/hip_runtime.h>
#include <cstdint>
#include <cstddef>

// ---------------- workspace layout (bytes) ----------------
// act   : uint64[4][8][9][1024]  bit-packed activations ((a*8+b)*9+c)*1024+l
// wbits : uint64[256][9]         weight sign bits (1 = +1)
// T     : int[512][9]            per-(b,ch) rect partial sums
// flag  : int[256]               BN fast flag per output channel
// wbyte : int8[9][256][64]       weight +-1 bytes (MFMA A-operand)
// (negS1/cq/flagF/MUG now computed per-block in k_out's prologue — the
//  9-block k_s1 dispatch is eliminated; 2 dispatches total)
static const size_t OFF_ACT  = 0;                  // 2359296
static const size_t OFF_W    = OFF_ACT + 2359296;  // 18432
static const size_t OFF_T    = OFF_W   + 18432;    // 18432
static const size_t OFF_FLAG = OFF_T   + 18432;    // 1024
static const size_t OFF_WB   = OFF_FLAG + 1024;    // 147456

typedef int v4i __attribute__((ext_vector_type(4)));

// integer sgn: exact for ints, folds to v_med3_i32
__device__ __forceinline__ int isgn(int e) {
  int t = e < -1 ? -1 : e;
  return t > 1 ? 1 : t;
}

// fused prep: [0,512) quant+rect; [512,1664) act bit-pack (LDS-staged);
// [1664,1728) wpack(+wbyte)
__global__ __launch_bounds__(256) void k_prep(const float* __restrict__ x,
                                              const float* __restrict__ w,
                                              const float* __restrict__ gamma,
                                              const float* __restrict__ beta,
                                              int* __restrict__ T,
                                              uint64_t* __restrict__ act,
                                              uint64_t* __restrict__ wbits,
                                              int* __restrict__ flag,
                                              signed char* __restrict__ wbyte) {
  int bid = blockIdx.x;
  int tid = threadIdx.x;
  if (bid < 512) {
    // ---- rect: quantize + 9 shifted-window popc partial sums per (b,ch) ----
    int base = bid << 10;
    int vals[9];
#pragma unroll
    for (int k = 0; k < 9; ++k) vals[k] = 0;
#pragma unroll
    for (int i = 0; i < 4; ++i) {
      int px = tid + i * 256;
      int h = px >> 5, ww = px & 31;
      float v = x[base + px];
      v = fminf(fmaxf(v, 0.f), 1.f);
      int q = (int)rintf(v * 15.f);
      int pc = __popc((unsigned)q);
      vals[0] += pc;
      if (h == 0) vals[1] += pc;
      if (h == 31) vals[2] += pc;
      if (ww == 0) vals[3] += pc;
      if (ww == 31) vals[4] += pc;
      if (h == 0 && ww == 0) vals[5] += pc;
      if (h == 0 && ww == 31) vals[6] += pc;
      if (h == 31 && ww == 0) vals[7] += pc;
      if (h == 31 && ww == 31) vals[8] += pc;
    }
#pragma unroll
    for (int k = 0; k < 9; ++k)
      for (int off = 32; off; off >>= 1) vals[k] += __shfl_down(vals[k], off, 64);
    __shared__ int red[4][9];
    int wid = tid >> 6, lane = tid & 63;
    if (lane == 0)
#pragma unroll
      for (int k = 0; k < 9; ++k) red[wid][k] = vals[k];
    __syncthreads();
    if (tid < 9) T[bid * 9 + tid] = red[0][tid] + red[1][tid] + red[2][tid] + red[3][tid];
  } else if (bid < 1664) {
    // ---- apack: LDS-staged; one block = 64 l-px of one (b,c) chunk ----
    int blk = bid - 512;             // 0..1151
    int bc = blk >> 4;               // b*9+c
    int c = bc % 9, b = bc / 9;
    int l0 = (blk & 15) << 6;        // 64-aligned
    int h0 = l0 >> 5;                // even; block rows h0, h0+1
    int chLo = (c * 64) / 9;         // window spans exactly 8 channels
    __shared__ unsigned char qlds[8][4][34];  // [ch][row h0-1+ri][w+1], halo=0
    for (int e = tid; e < 1024; e += 256) {
      int ci = e >> 7, rem = e & 127, ri = rem >> 5, wi = rem & 31;
      int hh = h0 - 1 + ri;
      int qv = 0;
      if ((unsigned)hh < 32u) {
        float v = x[((b * 64 + chLo + ci) << 10) + (hh << 5) + wi];
        v = fminf(fmaxf(v, 0.f), 1.f);
        qv = (int)rintf(v * 15.f);
      }
      qlds[ci][ri][wi + 1] = (unsigned char)qv;
      if (wi == 0) qlds[ci][ri][0] = 0;
      if (wi == 31) qlds[ci][ri][33] = 0;
    }
    __syncthreads();

    int half = tid & 3;              // j-quarter
    int dl = tid >> 2;               // 0..63
    int l = l0 + dl;
    int h = l >> 5, w0 = l & 31;
    int hr = h - h0;                 // 0 or 1
    int i9 = c * 64 + half * 16;
    int ch = i9 / 9;
    int k = i9 - ch * 9;
    int ki = k / 3, kj = k - ki * 3;
    int cch = ch - chLo;             // 0..7
    unsigned m0 = 0, m1 = 0, m2 = 0, m3 = 0;
#pragma unroll
    for (int jj = 0; jj < 16; ++jj) {
      int q = qlds[cch][hr + ki][w0 + kj];
      m0 |= (unsigned)(q & 1) << jj;
      m1 |= (unsigned)((q >> 1) & 1) << jj;
      m2 |= (unsigned)((q >> 2) & 1) << jj;
      m3 |= (unsigned)((q >> 3) & 1) << jj;
      if (++kj == 3) { kj = 0; if (++ki == 3) { ki = 0; ++cch; } }
    }
    size_t stride = 8 * 9 * 1024;
    size_t off = ((size_t)b * 9 + c) * 1024 + l;
    unsigned short* a16 = (unsigned short*)act;
    a16[(0 * stride + off) * 4 + half] = (unsigned short)m0;
    a16[(1 * stride + off) * 4 + half] = (unsigned short)m1;
    a16[(2 * stride + off) * 4 + half] = (unsigned short)m2;
    a16[(3 * stride + off) * 4 + half] = (unsigned short)m3;
  } else {
    // ---- wpack: one wave per output channel (4 per block) ----
    int lane = tid & 63;
    int wid = tid >> 6;
    int o = (bid - 1664) * 4 + wid;
    const float* row = w + (size_t)o * 576;
    double s = 0.0;
#pragma unroll
    for (int i = 0; i < 9; ++i) s += (double)row[lane + i * 64];
    for (int off = 32; off; off >>= 1) s += __shfl_down(s, off, 64);
    s = __shfl(s, 0, 64);
    float mean = (float)(s / 576.0);
#pragma unroll
    for (int c = 0; c < 9; ++c) {
      float v = row[c * 64 + lane];
      int pos = (v - mean) > 0.f;
      unsigned long long m = __ballot(pos);
      if (lane == 0) wbits[o * 9 + c] = (uint64_t)m;
      wbyte[(c * 256 + o) * 64 + lane] = pos ? (signed char)1 : (signed char)-1;
    }
    if (lane == 0) flag[o] = (beta[o] == 0.f && gamma[o] > 0.f) ? 1 : 0;
  }
}

// MFMA output kernel (R12): R11 a-split body + fused k_s1 prologue.
// Each block recomputes T-aggregate -> U -> S1 for ALL 2304 (o,c) pairs
// into LDS (cqsh / nS1sh / flagFsh / gated MUGsh) -- verbatim k_s1 math,
// ~0.3us redundancy per block -- eliminating the 9-block k_s1 dispatch
// and one launch+drain hop. LDS total ~58KB -> 2 blocks/CU (4 waves/SIMD).
__global__ __launch_bounds__(512, 4) void k_out(const uint64_t* __restrict__ act,
                                                const uint64_t* __restrict__ wbits,
                                                const signed char* __restrict__ wbyte,
                                                const int* __restrict__ T,
                                                const int* __restrict__ flag,
                                                const float* __restrict__ gamma,
                                                const float* __restrict__ beta,
                                                float* __restrict__ out) {
  __shared__ int Tsh[576];
  __shared__ int Ush[9 * 65];
  __shared__ __align__(16) int cqsh[2304];   // [c*256+o] = -(S1>>15)
  __shared__ int nS1sh[2304];                // [c*256+o] = -S1
  __shared__ int flagFsh[256];               // flag && no tie across c
  __shared__ float2 MUGsh[2304];             // [o*9+c], slow path only
  __shared__ unsigned int part[4][16][65];   // a-split combine, padded
  int tid = threadIdx.x;
  int lt = blockIdx.x;  // 0..63 (16 px each)
  int b = blockIdx.y;   // 0..7

  // ---- prologue P1: T-aggregate + flagF init ----
  for (int i = tid; i < 576; i += 512) {
    int acc = 0;
#pragma unroll
    for (int bb = 0; bb < 8; ++bb) acc += T[bb * 576 + i];
    Tsh[i] = acc;
  }
  for (int o = tid; o < 256; o += 512) flagFsh[o] = flag[o];
  __syncthreads();
  // ---- prologue P2: rect -> U transform (k_s1 verbatim, stride 512) ----
  for (int i = tid; i < 576; i += 512) {
    int ch = i / 9;
    int k = i - ch * 9;
    int ki = k / 3, kj = k - ki * 3;
    const int* t = &Tsh[ch * 9];
    int u = t[0];
    if (ki == 0) u -= t[2]; else if (ki == 2) u -= t[1];
    if (kj == 0) u -= t[4]; else if (kj == 2) u -= t[3];
    if (ki == 0 && kj == 0) u += t[8];
    if (ki == 0 && kj == 2) u += t[7];
    if (ki == 2 && kj == 0) u += t[6];
    if (ki == 2 && kj == 2) u += t[5];
    Ush[(i >> 6) * 65 + (i & 63)] = u;
  }
  __syncthreads();
  // ---- prologue P3: S1 per (o,c) pair (k_s1 verbatim, stride 512) ----
  for (int pair = tid; pair < 2304; pair += 512) {
    int o = pair / 9, c = pair - o * 9;
    uint64_t wv = wbits[pair];
    int tot = 0, pos = 0;
#pragma unroll 8
    for (int j = 0; j < 64; ++j) {
      int cnt = Ush[c * 65 + j];
      tot += cnt;
      if ((wv >> j) & 1) pos += cnt;
    }
    int s1 = 2 * pos - tot;
    nS1sh[c * 256 + o] = -s1;
    cqsh[c * 256 + o] = -(s1 >> 15);
    if ((s1 & 32767) == 0) atomicAnd(&flagFsh[o], 0);  // exact-tie -> general path
    if (!flag[o]) {  // gated BN slow path (never taken with this data)
      int s2 = 0;
      for (int i = 0; i < 32768; ++i) {
        uint64_t av = act[((size_t)(i >> 10) * 9 + c) * 1024 + (i & 1023)];
        int lin = 2 * __popcll(av & wv) - __popcll(av);
        s2 += lin * lin;
      }
      float mu = (float)s1 * (1.f / 32768.f);
      float ex2 = (float)s2 * (1.f / 32768.f);
      float var = ex2 - mu * mu;
      if (var < 0.f) var = 0.f;
      MUGsh[pair] = make_float2(mu, gamma[o] / sqrtf(var + 1e-5f));
    }
  }
  __syncthreads();

  // ---- body: R11 a-split structure (verbatim, LDS-sourced thresholds) ----
  int lane = tid & 63;
  int w8 = __builtin_amdgcn_readfirstlane(tid >> 6);  // 0..7
  int w = w8 & 3;        // tile-group
  int hi = w8 >> 2;      // 0: a={1,0} (weight 1), 1: a={3,2} (weight 4)
  int row = lane & 15;   // A row / B col / D col
  int g = lane >> 4;     // k-group 0..3
  int sh16 = (g & 1) * 16;
  int aBase = 2 * hi;

  int o0 = w * 32 + (lane & 31);
  int fb = flagFsh[o0] & flagFsh[o0 + 128];
  bool fastAll = (bool)__all(fb != 0);

  const v4i zacc = {0, 0, 0, 0};
  int l = lt * 16 + row;
  const char* actbyte = (const char*)act + ((size_t)b * 9 * 1024 + l) * 8 + (g >> 1) * 4;

  unsigned pt[16];  // partial payload (P[4][4] fast; M2|F2 general)

  if (fastAll) {
    int P[4][4];
#pragma unroll
    for (int q = 0; q < 4; ++q)
#pragma unroll
      for (int r = 0; r < 4; ++r) P[q][r] = 0;

    for (int c = 0; c < 9; ++c) {
      v4i Af[4], Cin[4];
#pragma unroll
      for (int q = 0; q < 4; ++q) {
        int ot = 2 * w + (q & 1) + (q >> 1) * 8;
        Af[q] = *(const v4i*)(wbyte + ((size_t)(c * 256 + ot * 16 + row) * 64 + g * 16));
        Cin[q] = *(const v4i*)&cqsh[c * 256 + ot * 16 + g * 4];  // ds_read_b128
      }
      unsigned dwv[2];
#pragma unroll
      for (int ai = 0; ai < 2; ++ai)
        dwv[ai] = *(const unsigned*)(actbyte +
                                     (size_t)(aBase + ai) * 589824 +
                                     (size_t)c * 8192);

      int pc[4][4];
#pragma unroll
      for (int q = 0; q < 4; ++q)
#pragma unroll
        for (int r = 0; r < 4; ++r) pc[q][r] = 0;

#pragma unroll
      for (int ai2 = 0; ai2 < 2; ++ai2) {   // ai = 1 then 0 (Horner desc)
        int ai = 1 - ai2;
        unsigned bits = (dwv[ai] >> sh16) & 0xFFFFu;
        v4i Bf;
#pragma unroll
        for (int d = 0; d < 4; ++d)
          Bf[d] = (int)((((bits >> (4 * d)) & 0xFu) * 0x00204081u) & 0x01010101u);
#pragma unroll
        for (int q = 0; q < 4; ++q) {
          v4i acc = __builtin_amdgcn_mfma_i32_16x16x64_i8(Af[q], Bf, Cin[q], 0, 0, 0);
#pragma unroll
          for (int r = 0; r < 4; ++r)
            pc[q][r] += pc[q][r] + (acc[r] > 0 ? 1 : 0);  // pc = 2pc + [acc>0]
        }
      }
#pragma unroll
      for (int q = 0; q < 4; ++q)
#pragma unroll
        for (int r = 0; r < 4; ++r) P[q][r] += pc[q][r];
    }
#pragma unroll
    for (int q = 0; q < 4; ++q)
#pragma unroll
      for (int r = 0; r < 4; ++r) pt[q * 4 + r] = (unsigned)P[q][r];
  } else {
    // ---- general path (never taken with this data); exact med3 route ----
    int M2[2][4] = {{0, 0, 0, 0}, {0, 0, 0, 0}};
    float F2[2][4] = {{0.f, 0.f, 0.f, 0.f}, {0.f, 0.f, 0.f, 0.f}};
    int flv[4][4];
#pragma unroll
    for (int q = 0; q < 4; ++q) {
      int ot = 2 * w + (q & 1) + (q >> 1) * 8;
#pragma unroll
      for (int r = 0; r < 4; ++r) flv[q][r] = flag[ot * 16 + g * 4 + r];
    }
    for (int c = 0; c < 9; ++c) {
      v4i Af[4];
      int nS[4][4];
#pragma unroll
      for (int q = 0; q < 4; ++q) {
        int ot = 2 * w + (q & 1) + (q >> 1) * 8;
        Af[q] = *(const v4i*)(wbyte + ((size_t)(c * 256 + ot * 16 + row) * 64 + g * 16));
#pragma unroll
        for (int r = 0; r < 4; ++r) nS[q][r] = nS1sh[c * 256 + ot * 16 + g * 4 + r];
      }
      unsigned dwv[2];
#pragma unroll
      for (int ai = 0; ai < 2; ++ai)
        dwv[ai] = *(const unsigned*)(actbyte +
                                     (size_t)(aBase + ai) * 589824 +
                                     (size_t)c * 8192);
#pragma unroll
      for (int ai = 0; ai < 2; ++ai) {
        unsigned bits = (dwv[ai] >> sh16) & 0xFFFFu;
        v4i Bf;
#pragma unroll
        for (int d = 0; d < 4; ++d)
          Bf[d] = (int)((((bits >> (4 * d)) & 0xFu) * 0x00204081u) & 0x01010101u);
#pragma unroll
        for (int q = 0; q < 4; ++q) {
          v4i acc = __builtin_amdgcn_mfma_i32_16x16x64_i8(Af[q], Bf, zacc, 0, 0, 0);
          int ot = 2 * w + (q & 1) + (q >> 1) * 8;
#pragma unroll
          for (int r = 0; r < 4; ++r) {
            int lin = acc[r];
            if (flv[q][r]) {
              M2[q & 1][r] += isgn((lin << 15) + nS[q][r]) << (ai + (q >> 1));
            } else {
              int o = ot * 16 + g * 4 + r;
              float2 m2 = MUGsh[o * 9 + c];
              float bn = m2.y * ((float)lin - m2.x) + beta[o];
              float sg = (bn > 0.f) ? 1.f : ((bn < 0.f) ? -1.f : 0.f);
              F2[q & 1][r] += sg * (float)(1 << (ai + (q >> 1)));
            }
          }
        }
      }
    }
#pragma unroll
    for (int q2 = 0; q2 < 2; ++q2)
#pragma unroll
      for (int r = 0; r < 4; ++r) {
        pt[q2 * 4 + r] = (unsigned)M2[q2][r];
        pt[8 + q2 * 4 + r] = __float_as_uint(F2[q2][r]);
      }
  }

  if (hi) {
#pragma unroll
    for (int i = 0; i < 16; ++i) part[w][i][lane] = pt[i];
  }
  __syncthreads();
  if (!hi) {
    if (fastAll) {
      int Pf[4][4];
#pragma unroll
      for (int q = 0; q < 4; ++q)
#pragma unroll
        for (int r = 0; r < 4; ++r)
          Pf[q][r] = (int)pt[q * 4 + r] + 4 * (int)part[w][q * 4 + r][lane];
#pragma unroll
      for (int q2 = 0; q2 < 2; ++q2)
#pragma unroll
        for (int r = 0; r < 4; ++r) {
          int oo = (2 * w + q2) * 16 + g * 4 + r;
          int M = 2 * (Pf[q2][r] + 2 * Pf[q2 + 2][r]) - 405;
          out[((size_t)b * 128 + oo) * 1024 + l] = (float)M * (2.f / 45.f);
        }
    } else {
#pragma unroll
      for (int q2 = 0; q2 < 2; ++q2)
#pragma unroll
        for (int r = 0; r < 4; ++r) {
          int oo = (2 * w + q2) * 16 + g * 4 + r;
          int Mf = (int)pt[q2 * 4 + r] + 4 * (int)part[w][q2 * 4 + r][lane];
          float Ff = __uint_as_float(pt[8 + q2 * 4 + r]) +
                     4.f * __uint_as_float(part[w][8 + q2 * 4 + r][lane]);
          out[((size_t)b * 128 + oo) * 1024 + l] =
              ((float)Mf + Ff) * (2.f / 45.f);
        }
    }
  }
}

extern "C" void kernel_launch(void* const* d_in, const int* in_sizes, int n_in,
                              void* d_out, int out_size, void* d_ws, size_t ws_size,
                              hipStream_t stream) {
  const float* inputs = (const float*)d_in[0];
  const float* weight = (const float*)d_in[1];
  const float* gamma = (const float*)d_in[2];
  const float* beta = (const float*)d_in[3];
  float* out = (float*)d_out;

  char* ws = (char*)d_ws;
  uint64_t* act = (uint64_t*)(ws + OFF_ACT);
  uint64_t* wbits = (uint64_t*)(ws + OFF_W);
  int* T = (int*)(ws + OFF_T);
  int* flag = (int*)(ws + OFF_FLAG);
  signed char* wbyte = (signed char*)(ws + OFF_WB);

  k_prep<<<1728, 256, 0, stream>>>(inputs, weight, gamma, beta, T, act, wbits, flag, wbyte);
  k_out<<<dim3(64, 8), 512, 0, stream>>>(act, wbits, wbyte, T, flag, gamma, beta, out);
}

// Round 13
// 87.930 us; speedup vs baseline: 1.0792x; 1.0792x over previous
//
#include <hip/hip_runtime.h>
#include <cstdint>
#include <cstddef>

// ---------------- workspace layout (bytes) ----------------
// act   : uint64[4][8][9][1024]  bit-packed activations ((a*8+b)*9+c)*1024+l
// wbits : uint64[256][9]         weight sign bits (1 = +1)
// T     : int[512][9]            per-(b,ch) rect partial sums
// negS1 : int[9][256]            -S1 per (c,o)  (general-path threshold)
// MUG   : float2[2304]           (mu, gamma*rsqrt) slow path only, [o*9+c]
// flag  : int[256]               BN fast flag per output channel
// wbyte : int8[9][256][64]       weight +-1 bytes (MFMA A-operand)
// cq    : int[9][256]            -(S1>>15) per (c,o) (MFMA C_in threshold)
// flagF : int[256]               flag && no (S1&32767)==0 across c (fast gate)
static const size_t OFF_ACT  = 0;                  // 2359296
static const size_t OFF_W    = OFF_ACT + 2359296;  // 18432
static const size_t OFF_T    = OFF_W   + 18432;    // 18432
static const size_t OFF_NS1  = OFF_T   + 18432;    // 9216
static const size_t OFF_MUG  = OFF_NS1 + 9216;     // 18432
static const size_t OFF_FLAG = OFF_MUG + 18432;    // 1024
static const size_t OFF_WB   = OFF_FLAG + 1024;    // 147456
static const size_t OFF_CQ   = OFF_WB + 147456;    // 9216
static const size_t OFF_FF   = OFF_CQ + 9216;      // 1024

typedef int v4i __attribute__((ext_vector_type(4)));

// integer sgn: exact for ints, folds to v_med3_i32
__device__ __forceinline__ int isgn(int e) {
  int t = e < -1 ? -1 : e;
  return t > 1 ? 1 : t;
}

// fused prep: [0,512) quant+rect; [512,1664) act bit-pack (LDS-staged);
// [1664,1728) wpack(+wbyte)   -- R11 verbatim
__global__ __launch_bounds__(256) void k_prep(const float* __restrict__ x,
                                              const float* __restrict__ w,
                                              const float* __restrict__ gamma,
                                              const float* __restrict__ beta,
                                              int* __restrict__ T,
                                              uint64_t* __restrict__ act,
                                              uint64_t* __restrict__ wbits,
                                              int* __restrict__ flag,
                                              signed char* __restrict__ wbyte,
                                              int* __restrict__ flagF) {
  int bid = blockIdx.x;
  int tid = threadIdx.x;
  if (bid < 512) {
    // ---- rect: quantize + 9 shifted-window popc partial sums per (b,ch) ----
    int base = bid << 10;
    int vals[9];
#pragma unroll
    for (int k = 0; k < 9; ++k) vals[k] = 0;
#pragma unroll
    for (int i = 0; i < 4; ++i) {
      int px = tid + i * 256;
      int h = px >> 5, ww = px & 31;
      float v = x[base + px];
      v = fminf(fmaxf(v, 0.f), 1.f);
      int q = (int)rintf(v * 15.f);
      int pc = __popc((unsigned)q);
      vals[0] += pc;
      if (h == 0) vals[1] += pc;
      if (h == 31) vals[2] += pc;
      if (ww == 0) vals[3] += pc;
      if (ww == 31) vals[4] += pc;
      if (h == 0 && ww == 0) vals[5] += pc;
      if (h == 0 && ww == 31) vals[6] += pc;
      if (h == 31 && ww == 0) vals[7] += pc;
      if (h == 31 && ww == 31) vals[8] += pc;
    }
#pragma unroll
    for (int k = 0; k < 9; ++k)
      for (int off = 32; off; off >>= 1) vals[k] += __shfl_down(vals[k], off, 64);
    __shared__ int red[4][9];
    int wid = tid >> 6, lane = tid & 63;
    if (lane == 0)
#pragma unroll
      for (int k = 0; k < 9; ++k) red[wid][k] = vals[k];
    __syncthreads();
    if (tid < 9) T[bid * 9 + tid] = red[0][tid] + red[1][tid] + red[2][tid] + red[3][tid];
  } else if (bid < 1664) {
    // ---- apack: LDS-staged; one block = 64 l-px of one (b,c) chunk ----
    int blk = bid - 512;             // 0..1151
    int bc = blk >> 4;               // b*9+c
    int c = bc % 9, b = bc / 9;
    int l0 = (blk & 15) << 6;        // 64-aligned
    int h0 = l0 >> 5;                // even; block rows h0, h0+1
    int chLo = (c * 64) / 9;         // window spans exactly 8 channels
    __shared__ unsigned char qlds[8][4][34];  // [ch][row h0-1+ri][w+1], halo=0
    for (int e = tid; e < 1024; e += 256) {
      int ci = e >> 7, rem = e & 127, ri = rem >> 5, wi = rem & 31;
      int hh = h0 - 1 + ri;
      int qv = 0;
      if ((unsigned)hh < 32u) {
        float v = x[((b * 64 + chLo + ci) << 10) + (hh << 5) + wi];
        v = fminf(fmaxf(v, 0.f), 1.f);
        qv = (int)rintf(v * 15.f);
      }
      qlds[ci][ri][wi + 1] = (unsigned char)qv;
      if (wi == 0) qlds[ci][ri][0] = 0;
      if (wi == 31) qlds[ci][ri][33] = 0;
    }
    __syncthreads();

    int half = tid & 3;              // j-quarter
    int dl = tid >> 2;               // 0..63
    int l = l0 + dl;
    int h = l >> 5, w0 = l & 31;
    int hr = h - h0;                 // 0 or 1
    int i9 = c * 64 + half * 16;
    int ch = i9 / 9;
    int k = i9 - ch * 9;
    int ki = k / 3, kj = k - ki * 3;
    int cch = ch - chLo;             // 0..7
    unsigned m0 = 0, m1 = 0, m2 = 0, m3 = 0;
#pragma unroll
    for (int jj = 0; jj < 16; ++jj) {
      int q = qlds[cch][hr + ki][w0 + kj];
      m0 |= (unsigned)(q & 1) << jj;
      m1 |= (unsigned)((q >> 1) & 1) << jj;
      m2 |= (unsigned)((q >> 2) & 1) << jj;
      m3 |= (unsigned)((q >> 3) & 1) << jj;
      if (++kj == 3) { kj = 0; if (++ki == 3) { ki = 0; ++cch; } }
    }
    size_t stride = 8 * 9 * 1024;
    size_t off = ((size_t)b * 9 + c) * 1024 + l;
    unsigned short* a16 = (unsigned short*)act;
    a16[(0 * stride + off) * 4 + half] = (unsigned short)m0;
    a16[(1 * stride + off) * 4 + half] = (unsigned short)m1;
    a16[(2 * stride + off) * 4 + half] = (unsigned short)m2;
    a16[(3 * stride + off) * 4 + half] = (unsigned short)m3;
  } else {
    // ---- wpack: one wave per output channel (4 per block) ----
    int lane = tid & 63;
    int wid = tid >> 6;
    int o = (bid - 1664) * 4 + wid;
    const float* row = w + (size_t)o * 576;
    double s = 0.0;
#pragma unroll
    for (int i = 0; i < 9; ++i) s += (double)row[lane + i * 64];
    for (int off = 32; off; off >>= 1) s += __shfl_down(s, off, 64);
    s = __shfl(s, 0, 64);
    float mean = (float)(s / 576.0);
#pragma unroll
    for (int c = 0; c < 9; ++c) {
      float v = row[c * 64 + lane];
      int pos = (v - mean) > 0.f;
      unsigned long long m = __ballot(pos);
      if (lane == 0) wbits[o * 9 + c] = (uint64_t)m;
      wbyte[(c * 256 + o) * 64 + lane] = pos ? (signed char)1 : (signed char)-1;
    }
    if (lane == 0) {
      int f = (beta[o] == 0.f && gamma[o] > 0.f) ? 1 : 0;
      flag[o] = f;
      flagF[o] = f;  // k_s1 will atomicAnd-clear if any (c,o) has rem==0
    }
  }
}

// S1 kernel (R13): parallelized 4x. Grid 36 blocks x 256 thr; 4 threads per
// (o,c) pair, each covering 16 j's of the dot, combined with two
// __shfl_down(.,width=4) lane-group reduces. T-aggregate + U-transform
// verbatim per block (redundant 4.6KB L2 reads, trivial). Was 9 blocks
// (3.5% of CUs, serial 64-iter dot/thread ~= 3-4us latency dispatch).
__global__ __launch_bounds__(256) void k_s1(const int* __restrict__ T,
                                            const uint64_t* __restrict__ wbits,
                                            const int* __restrict__ flag,
                                            const float* __restrict__ gamma,
                                            const uint64_t* __restrict__ act,
                                            int* __restrict__ negS1,
                                            int* __restrict__ cq,
                                            int* __restrict__ flagF,
                                            float2* __restrict__ MUG) {
  __shared__ int Tsh[576];
  __shared__ int Ush[9 * 65];
  int tid = threadIdx.x;
  for (int i = tid; i < 576; i += 256) {
    int acc = 0;
#pragma unroll
    for (int b = 0; b < 8; ++b) acc += T[b * 576 + i];
    Tsh[i] = acc;
  }
  __syncthreads();
  for (int i = tid; i < 576; i += 256) {
    int ch = i / 9;
    int k = i - ch * 9;
    int ki = k / 3, kj = k - ki * 3;
    const int* t = &Tsh[ch * 9];
    int u = t[0];
    if (ki == 0) u -= t[2]; else if (ki == 2) u -= t[1];
    if (kj == 0) u -= t[4]; else if (kj == 2) u -= t[3];
    if (ki == 0 && kj == 0) u += t[8];
    if (ki == 0 && kj == 2) u += t[7];
    if (ki == 2 && kj == 0) u += t[6];
    if (ki == 2 && kj == 2) u += t[5];
    Ush[(i >> 6) * 65 + (i & 63)] = u;  // chunk c = i/64, j = i%64
  }
  __syncthreads();
  int pair = blockIdx.x * 64 + (tid >> 2);  // 36 x 64 = 2304
  int qt = tid & 3;                         // j-quarter of the dot
  int o = pair / 9, c = pair - o * 9;
  uint64_t wv = wbits[pair];
  int tot = 0, pos = 0;
#pragma unroll
  for (int jj = 0; jj < 16; ++jj) {
    int j = qt * 16 + jj;
    int cnt = Ush[c * 65 + j];
    tot += cnt;
    if ((wv >> j) & 1) pos += cnt;
  }
  tot += __shfl_down(tot, 2, 4); tot += __shfl_down(tot, 1, 4);
  pos += __shfl_down(pos, 2, 4); pos += __shfl_down(pos, 1, 4);
  if (qt == 0) {
    int s1 = 2 * pos - tot;
    negS1[c * 256 + o] = -s1;
    cq[c * 256 + o] = -(s1 >> 15);          // floor-div threshold for MFMA C_in
    if ((s1 & 32767) == 0) atomicAnd(&flagF[o], 0);  // exact-tie -> general path
    if (!flag[o]) {  // gated BN slow path (never taken with this data)
      int s2 = 0;
      for (int i = 0; i < 32768; ++i) {
        uint64_t av = act[((size_t)(i >> 10) * 9 + c) * 1024 + (i & 1023)];
        int lin = 2 * __popcll(av & wv) - __popcll(av);
        s2 += lin * lin;
      }
      float mu = (float)s1 * (1.f / 32768.f);
      float ex2 = (float)s2 * (1.f / 32768.f);
      float var = ex2 - mu * mu;
      if (var < 0.f) var = 0.f;
      MUG[pair] = make_float2(mu, gamma[o] / sqrtf(var + 1e-5f));
    }
  }
}

// MFMA output kernel (R11 verbatim — 88.1us champion): a-split 8 waves,
// C_in threshold fold, plain-C predicate Horner, LDS combine (x4 weight).
__global__ __launch_bounds__(512, 4) void k_out(const uint64_t* __restrict__ act,
                                                const signed char* __restrict__ wbyte,
                                                const int* __restrict__ negS1g,
                                                const int* __restrict__ cqg,
                                                const float2* __restrict__ MUG,
                                                const int* __restrict__ flag,
                                                const int* __restrict__ flagF,
                                                const float* __restrict__ beta,
                                                float* __restrict__ out) {
  __shared__ __align__(16) int cqsh[2304];
  __shared__ unsigned int part[4][16][65];  // [w][payload idx][lane], padded
  int tid = threadIdx.x;
  int lt = blockIdx.x;  // 0..63 (16 px each)
  int b = blockIdx.y;   // 0..7
  for (int i = tid; i < 2304; i += 512) cqsh[i] = cqg[i];
  __syncthreads();

  int lane = tid & 63;
  int w8 = __builtin_amdgcn_readfirstlane(tid >> 6);  // 0..7
  int w = w8 & 3;        // tile-group
  int hi = w8 >> 2;      // 0: a={1,0} (weight 1), 1: a={3,2} (weight 4)
  int row = lane & 15;   // A row / B col / D col
  int g = lane >> 4;     // k-group 0..3
  int sh16 = (g & 1) * 16;
  int aBase = 2 * hi;

  // wave-uniform fast-path check (identical for partner waves w, w+4)
  int o0 = w * 32 + (lane & 31);
  int fb = flagF[o0] & flagF[o0 + 128];
  bool fastAll = (bool)__all(fb != 0);

  const v4i zacc = {0, 0, 0, 0};
  int l = lt * 16 + row;
  const char* actbyte = (const char*)act + ((size_t)b * 9 * 1024 + l) * 8 + (g >> 1) * 4;

  unsigned pt[16];  // partial payload (P[4][4] fast; M2|F2 general)

  if (fastAll) {
    int P[4][4];
#pragma unroll
    for (int q = 0; q < 4; ++q)
#pragma unroll
      for (int r = 0; r < 4; ++r) P[q][r] = 0;

    for (int c = 0; c < 9; ++c) {
      v4i Af[4], Cin[4];
#pragma unroll
      for (int q = 0; q < 4; ++q) {
        int ot = 2 * w + (q & 1) + (q >> 1) * 8;
        Af[q] = *(const v4i*)(wbyte + ((size_t)(c * 256 + ot * 16 + row) * 64 + g * 16));
        Cin[q] = *(const v4i*)&cqsh[c * 256 + ot * 16 + g * 4];  // ds_read_b128
      }
      unsigned dwv[2];
#pragma unroll
      for (int ai = 0; ai < 2; ++ai)
        dwv[ai] = *(const unsigned*)(actbyte +
                                     (size_t)(aBase + ai) * 589824 +
                                     (size_t)c * 8192);

      int pc[4][4];
#pragma unroll
      for (int q = 0; q < 4; ++q)
#pragma unroll
        for (int r = 0; r < 4; ++r) pc[q][r] = 0;

#pragma unroll
      for (int ai2 = 0; ai2 < 2; ++ai2) {   // ai = 1 then 0 (Horner desc)
        int ai = 1 - ai2;
        unsigned bits = (dwv[ai] >> sh16) & 0xFFFFu;
        v4i Bf;
#pragma unroll
        for (int d = 0; d < 4; ++d)
          Bf[d] = (int)((((bits >> (4 * d)) & 0xFu) * 0x00204081u) & 0x01010101u);
#pragma unroll
        for (int q = 0; q < 4; ++q) {
          v4i acc = __builtin_amdgcn_mfma_i32_16x16x64_i8(Af[q], Bf, Cin[q], 0, 0, 0);
#pragma unroll
          for (int r = 0; r < 4; ++r)
            pc[q][r] += pc[q][r] + (acc[r] > 0 ? 1 : 0);  // pc = 2pc + [acc>0]
        }
      }
#pragma unroll
      for (int q = 0; q < 4; ++q)
#pragma unroll
        for (int r = 0; r < 4; ++r) P[q][r] += pc[q][r];
    }
#pragma unroll
    for (int q = 0; q < 4; ++q)
#pragma unroll
      for (int r = 0; r < 4; ++r) pt[q * 4 + r] = (unsigned)P[q][r];
  } else {
    // ---- general path (never taken with this data); exact med3 route ----
    int M2[2][4] = {{0, 0, 0, 0}, {0, 0, 0, 0}};
    float F2[2][4] = {{0.f, 0.f, 0.f, 0.f}, {0.f, 0.f, 0.f, 0.f}};
    int flv[4][4];
#pragma unroll
    for (int q = 0; q < 4; ++q) {
      int ot = 2 * w + (q & 1) + (q >> 1) * 8;
#pragma unroll
      for (int r = 0; r < 4; ++r) flv[q][r] = flag[ot * 16 + g * 4 + r];
    }
    for (int c = 0; c < 9; ++c) {
      v4i Af[4];
      int nS[4][4];
#pragma unroll
      for (int q = 0; q < 4; ++q) {
        int ot = 2 * w + (q & 1) + (q >> 1) * 8;
        Af[q] = *(const v4i*)(wbyte + ((size_t)(c * 256 + ot * 16 + row) * 64 + g * 16));
#pragma unroll
        for (int r = 0; r < 4; ++r) nS[q][r] = negS1g[c * 256 + ot * 16 + g * 4 + r];
      }
      unsigned dwv[2];
#pragma unroll
      for (int ai = 0; ai < 2; ++ai)
        dwv[ai] = *(const unsigned*)(actbyte +
                                     (size_t)(aBase + ai) * 589824 +
                                     (size_t)c * 8192);
#pragma unroll
      for (int ai = 0; ai < 2; ++ai) {
        unsigned bits = (dwv[ai] >> sh16) & 0xFFFFu;
        v4i Bf;
#pragma unroll
        for (int d = 0; d < 4; ++d)
          Bf[d] = (int)((((bits >> (4 * d)) & 0xFu) * 0x00204081u) & 0x01010101u);
#pragma unroll
        for (int q = 0; q < 4; ++q) {
          v4i acc = __builtin_amdgcn_mfma_i32_16x16x64_i8(Af[q], Bf, zacc, 0, 0, 0);
          int ot = 2 * w + (q & 1) + (q >> 1) * 8;
#pragma unroll
          for (int r = 0; r < 4; ++r) {
            int lin = acc[r];
            if (flv[q][r]) {
              M2[q & 1][r] += isgn((lin << 15) + nS[q][r]) << (ai + (q >> 1));
            } else {
              int o = ot * 16 + g * 4 + r;
              float2 m2 = MUG[o * 9 + c];
              float bn = m2.y * ((float)lin - m2.x) + beta[o];
              float sg = (bn > 0.f) ? 1.f : ((bn < 0.f) ? -1.f : 0.f);
              F2[q & 1][r] += sg * (float)(1 << (ai + (q >> 1)));
            }
          }
        }
      }
    }
#pragma unroll
    for (int q2 = 0; q2 < 2; ++q2)
#pragma unroll
      for (int r = 0; r < 4; ++r) {
        pt[q2 * 4 + r] = (unsigned)M2[q2][r];
        pt[8 + q2 * 4 + r] = __float_as_uint(F2[q2][r]);
      }
  }

  if (hi) {
#pragma unroll
    for (int i = 0; i < 16; ++i) part[w][i][lane] = pt[i];
  }
  __syncthreads();
  if (!hi) {
    if (fastAll) {
      int Pf[4][4];
#pragma unroll
      for (int q = 0; q < 4; ++q)
#pragma unroll
        for (int r = 0; r < 4; ++r)
          Pf[q][r] = (int)pt[q * 4 + r] + 4 * (int)part[w][q * 4 + r][lane];
#pragma unroll
      for (int q2 = 0; q2 < 2; ++q2)
#pragma unroll
        for (int r = 0; r < 4; ++r) {
          int oo = (2 * w + q2) * 16 + g * 4 + r;
          int M = 2 * (Pf[q2][r] + 2 * Pf[q2 + 2][r]) - 405;
          out[((size_t)b * 128 + oo) * 1024 + l] = (float)M * (2.f / 45.f);
        }
    } else {
#pragma unroll
      for (int q2 = 0; q2 < 2; ++q2)
#pragma unroll
        for (int r = 0; r < 4; ++r) {
          int oo = (2 * w + q2) * 16 + g * 4 + r;
          int Mf = (int)pt[q2 * 4 + r] + 4 * (int)part[w][q2 * 4 + r][lane];
          float Ff = __uint_as_float(pt[8 + q2 * 4 + r]) +
                     4.f * __uint_as_float(part[w][8 + q2 * 4 + r][lane]);
          out[((size_t)b * 128 + oo) * 1024 + l] =
              ((float)Mf + Ff) * (2.f / 45.f);
        }
    }
  }
}

extern "C" void kernel_launch(void* const* d_in, const int* in_sizes, int n_in,
                              void* d_out, int out_size, void* d_ws, size_t ws_size,
                              hipStream_t stream) {
  const float* inputs = (const float*)d_in[0];
  const float* weight = (const float*)d_in[1];
  const float* gamma = (const float*)d_in[2];
  const float* beta = (const float*)d_in[3];
  float* out = (float*)d_out;

  char* ws = (char*)d_ws;
  uint64_t* act = (uint64_t*)(ws + OFF_ACT);
  uint64_t* wbits = (uint64_t*)(ws + OFF_W);
  int* T = (int*)(ws + OFF_T);
  int* negS1 = (int*)(ws + OFF_NS1);
  float2* MUG = (float2*)(ws + OFF_MUG);
  int* flag = (int*)(ws + OFF_FLAG);
  signed char* wbyte = (signed char*)(ws + OFF_WB);
  int* cq = (int*)(ws + OFF_CQ);
  int* flagF = (int*)(ws + OFF_FF);

  k_prep<<<1728, 256, 0, stream>>>(inputs, weight, gamma, beta, T, act, wbits, flag, wbyte, flagF);
  k_s1<<<36, 256, 0, stream>>>(T, wbits, flag, gamma, act, negS1, cq, flagF, MUG);
  k_out<<<dim3(64, 8), 512, 0, stream>>>(act, wbyte, negS1, cq, MUG, flag, flagF, beta, out);
}